// Round 3
// baseline (490.104 us; speedup 1.0000x reference)
//
#include <hip/hip_runtime.h>
#include <hip/hip_bf16.h>
#include <stdint.h>

#define B_    8
#define S_    4096
#define D_    1536
#define ORG_  4
#define OUT_  2048

typedef __bf16 bf16;
typedef __attribute__((ext_vector_type(8))) bf16  bf16x8;
typedef __attribute__((ext_vector_type(4))) float f32x4;

#define BK64 64
#define NKT  (D_ / BK64)   // 24 K-tiles per output tile
#define ROUNDS 4           // output tiles per persistent block

// ---------------- convert x: f32 -> bf16 (8 elems/thread/iter) --------------
__global__ void k_cvt_x(const float* __restrict__ x, bf16* __restrict__ xb, long n8) {
  long i = (long)blockIdx.x * blockDim.x + threadIdx.x;
  long stride = (long)gridDim.x * blockDim.x;
  for (; i < n8; i += stride) {
    const float4* p = (const float4*)(x + i * 8);
    float4 a = p[0];
    float4 b = p[1];
    bf16x8 v;
    v[0] = (bf16)a.x; v[1] = (bf16)a.y; v[2] = (bf16)a.z; v[3] = (bf16)a.w;
    v[4] = (bf16)b.x; v[5] = (bf16)b.y; v[6] = (bf16)b.z; v[7] = (bf16)b.w;
    *(bf16x8*)(xb + i * 8) = v;
  }
}

// ------ convert + transpose w: f32 [ORG][D][OUT] -> bf16 [ORG][OUT][D] ------
__global__ void k_cvt_wT(const float* __restrict__ w, bf16* __restrict__ wt) {
  __shared__ float tile[32][33];
  int org = blockIdx.z;
  int n0 = blockIdx.x * 32;   // OUT dim
  int d0 = blockIdx.y * 32;   // D dim
  const float* wsrc = w + (size_t)org * D_ * OUT_;
  bf16* wdst = wt + (size_t)org * OUT_ * D_;
  int tx = threadIdx.x, ty = threadIdx.y;
#pragma unroll
  for (int j = 0; j < 32; j += 8)
    tile[ty + j][tx] = wsrc[(size_t)(d0 + ty + j) * OUT_ + (n0 + tx)];
  __syncthreads();
#pragma unroll
  for (int j = 0; j < 32; j += 8)
    wdst[(size_t)(n0 + ty + j) * D_ + (d0 + tx)] = (bf16)tile[tx][ty + j];
}

// ---- persistent 256x256 8-phase bf16 MFMA GEMM, continuous K-stream --------
// A = xb[batch] : [S][D];  B = wt[org] : [OUT][D]  (both row-major, K inner)
// Each block owns 4 output tiles; the 8-phase schedule streams 96 K-tiles
// with no pipeline drain at tile boundaries.
__global__ __launch_bounds__(512, 2)
void k_gemm_pers(const bf16* __restrict__ xb, const bf16* __restrict__ wt,
                 const int* __restrict__ oidx, const float* __restrict__ bias,
                 float* __restrict__ out) {
  __shared__ __align__(16) char smem[131072];   // A: 2x32KB, B: 2x32KB
  char* const ldsA = smem;
  char* const ldsB = smem + 65536;

  const int bx = blockIdx.x;
  // T1: XCD-contiguous stream mapping. Round r: G = gbase + 256r;
  // pair = G>>4 -> (batch = pair>>3, tn = pair&7), tm = G&15.
  // XCD x (= bx&7) covers 2 fixed (batch,tn) B-panels per round.
  const int gbase = (bx & 7) * 32 + (bx >> 3);

  const bf16* AgR[ROUNDS]; const bf16* BgR[ROUNDS];
  float* OgR[ROUNDS]; const float* bbR[ROUNDS];
#pragma unroll
  for (int r = 0; r < ROUNDS; ++r) {
    const int G = gbase + r * 256;
    const int pair = G >> 4, tm = G & 15;
    const int batch = pair >> 3, tn = pair & 7;
    const int m0 = tm * 256, n0 = tn * 256;
    const int org = oidx[batch];
    AgR[r] = xb + (size_t)batch * S_ * D_ + (size_t)m0 * D_;
    BgR[r] = wt + (size_t)org * OUT_ * D_ + (size_t)n0 * D_;
    OgR[r] = out + (size_t)batch * S_ * OUT_ + (size_t)m0 * OUT_ + n0;
    bbR[r] = bias + (size_t)org * OUT_ + n0;
  }

  const int tid  = threadIdx.x;
  const int lane = tid & 63, wv = tid >> 6;
  const int wr = wv >> 2, wc = wv & 3;        // 2x4 wave grid, per-wave 128x64 out
  const int lm = lane & 15, lk = lane >> 4;

  // T2 read-side XOR swizzle (byte ^= (row&7)<<4 within 128B rows)
  const int xo0 = (lk * 16) ^ ((lm & 7) << 4);
  const int xo1 = (64 + lk * 16) ^ ((lm & 7) << 4);
  const int arow = (wr * 128 + lm) * 128;
  const int brow = (wc * 64  + lm) * 128;

  // Stage-side: linear LDS dest + inverse-swizzled per-lane GLOBAL source
  const int srow = tid >> 3;
  const int scol = ((tid & 7) ^ ((tid >> 3) & 7)) << 3;
  const int soff = wv * 1024;

#define LDA(v, mi, kk) (*(const bf16x8*)(ldsA + (v)*32768 + arow + (mi)*2048 + ((kk) ? xo1 : xo0)))
#define LDB(v, ni, kk) (*(const bf16x8*)(ldsB + (v)*32768 + brow + (ni)*2048 + ((kk) ? xo1 : xo0)))

#define STAGE_HALF(gptr, ldsbase, h, kb) do {                                            \
    __builtin_amdgcn_global_load_lds(                                                    \
      (__attribute__((address_space(1))) void*)((gptr) + (size_t)((h)*128 + srow) * D_ + (kb) + scol), \
      (__attribute__((address_space(3))) void*)((ldsbase) + (h)*16384 + soff), 16, 0, 0);\
    __builtin_amdgcn_global_load_lds(                                                    \
      (__attribute__((address_space(1))) void*)((gptr) + (size_t)((h)*128 + 64 + srow) * D_ + (kb) + scol), \
      (__attribute__((address_space(3))) void*)((ldsbase) + (h)*16384 + 8192 + soff), 16, 0, 0); \
  } while (0)

#define SBAR()  __builtin_amdgcn_s_barrier()
#define LGK0()  asm volatile("s_waitcnt lgkmcnt(0)" ::: "memory")
#define LGK8()  asm volatile("s_waitcnt lgkmcnt(8)" ::: "memory")
#define VMC4()  asm volatile("s_waitcnt vmcnt(4)" ::: "memory")
#define VMC0()  asm volatile("s_waitcnt vmcnt(0)" ::: "memory")
#define PRIO(p) __builtin_amdgcn_s_setprio(p)

  bf16x8 a[4][2], b0[2][2], b1[2][2];
  f32x4 acc[8][4];
#pragma unroll
  for (int m = 0; m < 8; ++m)
#pragma unroll
    for (int n = 0; n < 4; ++n) acc[m][n] = (f32x4){0.f, 0.f, 0.f, 0.f};

#define READ_A(v, mb) do { _Pragma("unroll") for (int m = 0; m < 4; ++m) { \
    a[m][0] = LDA(v, (mb) + m, 0); a[m][1] = LDA(v, (mb) + m, 1); } } while (0)
#define READ_B(v, nb, bb) do { _Pragma("unroll") for (int n = 0; n < 2; ++n) { \
    bb[n][0] = LDB(v, (nb) + n, 0); bb[n][1] = LDB(v, (nb) + n, 1); } } while (0)
#define MFMA_Q(mb, nb, bb) do { \
    _Pragma("unroll") for (int m = 0; m < 4; ++m) \
    _Pragma("unroll") for (int n = 0; n < 2; ++n) \
    _Pragma("unroll") for (int kk = 0; kk < 2; ++kk) \
      acc[(mb)+m][(nb)+n] = __builtin_amdgcn_mfma_f32_16x16x32_bf16( \
          a[m][kk], bb[n][kk], acc[(mb)+m][(nb)+n], 0, 0, 0); } while (0)

#define EPILOGUE(OgP, bbP) do { \
    float* Og_ = (OgP); const float* bb_ = (bbP); \
    _Pragma("unroll") for (int n = 0; n < 4; ++n) { \
      const int col = wc * 64 + n * 16 + lm; \
      const float bv = bb_[col]; \
      _Pragma("unroll") for (int m = 0; m < 8; ++m) \
      _Pragma("unroll") for (int rr = 0; rr < 4; ++rr) { \
        const int row = wr * 128 + m * 16 + lk * 4 + rr; \
        Og_[(size_t)row * OUT_ + col] = acc[m][n][rr] + bv; \
      } \
    } \
    _Pragma("unroll") for (int m = 0; m < 8; ++m) \
    _Pragma("unroll") for (int n = 0; n < 4; ++n) acc[m][n] = (f32x4){0.f, 0.f, 0.f, 0.f}; \
  } while (0)

  // ---- prologue: stream tiles q=0 (B+A) and q=1 (B): 6 halves, allow
  // newest 2 halves (q=1 B) outstanding at the barrier.
  STAGE_HALF(BgR[0], ldsB, 0, 0);
  STAGE_HALF(BgR[0], ldsB, 1, 0);
  STAGE_HALF(AgR[0], ldsA, 0, 0);
  STAGE_HALF(AgR[0], ldsA, 1, 0);
  STAGE_HALF(BgR[0], ldsB + 32768, 0, BK64);
  STAGE_HALF(BgR[0], ldsB + 32768, 1, BK64);
  VMC4();
  SBAR();

#pragma unroll
  for (int r = 0; r < ROUNDS; ++r) {
    const bf16* const AgCur = AgR[r];
    const bf16* const BgCur = BgR[r];
    const bf16* const AgNxt = AgR[r < ROUNDS - 1 ? r + 1 : ROUNDS - 1];
    const bf16* const BgNxt = BgR[r < ROUNDS - 1 ? r + 1 : ROUNDS - 1];
    const bool last = (r == ROUNDS - 1);

    for (int j = 0; j < NKT / 2; ++j) {
      const int k1 = (2 * j + 1) * BK64;     // A(2j+1): always current round
      const bool cross = (j == NKT / 2 - 1); // q+2,q+3 spill into next round
      const bf16* const A2 = cross ? AgNxt : AgCur;
      const bf16* const B2 = cross ? BgNxt : BgCur;
      const bf16* const B3 = cross ? BgNxt : BgCur;
      const int k2 = cross ? (last ? (NKT - 1) * BK64 : 0) : (2 * j + 2) * BK64;
      const int k3 = cross ? (last ? (NKT - 1) * BK64 : BK64) : (2 * j + 3) * BK64;

      // P1: compute q=2j quad(m0-3 x n0-1); stage A-half0(2j+1) -> buf1
      READ_A(0, 0); READ_B(0, 0, b0);
      STAGE_HALF(AgCur, ldsA + 32768, 0, k1);
      LGK8();
      SBAR(); LGK0();
      PRIO(1); MFMA_Q(0, 0, b0); PRIO(0);
      SBAR();
      // P2: quad(m0-3 x n2-3); stage A-half1(2j+1) -> buf1
      READ_B(0, 2, b1);
      STAGE_HALF(AgCur, ldsA + 32768, 1, k1);
      SBAR(); LGK0();
      PRIO(1); MFMA_Q(0, 2, b1); PRIO(0);
      SBAR();
      // P3: quad(m4-7 x n0-1); stage B-half0(2j+2) -> buf0
      READ_A(0, 4);
      STAGE_HALF(B2, ldsB, 0, k2);
      SBAR(); LGK0();
      PRIO(1); MFMA_Q(4, 0, b0); PRIO(0);
      SBAR();
      // P4: quad(m4-7 x n2-3); stage B-half1(2j+2); checkpoint vmcnt(4)
      STAGE_HALF(B2, ldsB, 1, k2);
      SBAR();
      PRIO(1); MFMA_Q(4, 2, b1); PRIO(0);
      VMC4();
      SBAR();
      // P5: compute q=2j+1 quad(m0-3 x n0-1); stage A-half0(2j+2) -> buf0
      READ_A(1, 0); READ_B(1, 0, b0);
      STAGE_HALF(A2, ldsA, 0, k2);
      LGK8();
      SBAR(); LGK0();
      PRIO(1); MFMA_Q(0, 0, b0); PRIO(0);
      SBAR();
      // P6: quad(m0-3 x n2-3); stage A-half1(2j+2) -> buf0
      READ_B(1, 2, b1);
      STAGE_HALF(A2, ldsA, 1, k2);
      SBAR(); LGK0();
      PRIO(1); MFMA_Q(0, 2, b1); PRIO(0);
      SBAR();
      // P7: quad(m4-7 x n0-1); stage B-half0(2j+3) -> buf1
      READ_A(1, 4);
      STAGE_HALF(B3, ldsB + 32768, 0, k3);
      SBAR(); LGK0();
      PRIO(1); MFMA_Q(4, 0, b0); PRIO(0);
      SBAR();
      // P8: quad(m4-7 x n2-3); stage B-half1(2j+3); checkpoint vmcnt(4)
      STAGE_HALF(B3, ldsB + 32768, 1, k3);
      SBAR();
      PRIO(1); MFMA_Q(4, 2, b1); PRIO(0);
      VMC4();
      SBAR();
    }

    // per-round epilogue: stores overlap the next round's in-flight prefetch
    if (last) VMC0();
    EPILOGUE(OgR[r], bbR[r]);
  }

#undef LDA
#undef LDB
#undef STAGE_HALF
#undef SBAR
#undef LGK0
#undef LGK8
#undef VMC4
#undef VMC0
#undef PRIO
#undef READ_A
#undef READ_B
#undef MFMA_Q
#undef EPILOGUE
}

// ---------------- fallback: naive fp32 (only if ws too small) ---------------
__global__ void k_gemm_fallback(const float* __restrict__ x, const int* __restrict__ oidx,
                                const float* __restrict__ w, const float* __restrict__ bias,
                                float* __restrict__ out) {
  const int b = blockIdx.z;
  const int org = oidx[b];
  const int n = blockIdx.x * 64 + threadIdx.x;
  const int m = blockIdx.y * 4 + threadIdx.y;
  const float* xr = x + ((size_t)b * S_ + m) * D_;
  const float* wp = w + (size_t)org * D_ * OUT_ + n;
  float acc = 0.f;
  for (int k = 0; k < D_; ++k) acc += xr[k] * wp[(size_t)k * OUT_];
  out[((size_t)b * S_ + m) * OUT_ + n] = acc + bias[(size_t)org * OUT_ + n];
}

extern "C" void kernel_launch(void* const* d_in, const int* in_sizes, int n_in,
                              void* d_out, int out_size, void* d_ws, size_t ws_size,
                              hipStream_t stream) {
  const float* x    = (const float*)d_in[0];
  const int*   oidx = (const int*)d_in[1];
  const float* w    = (const float*)d_in[2];
  const float* bias = (const float*)d_in[3];
  float* out = (float*)d_out;

  const size_t xb_elems = (size_t)B_ * S_ * D_;      // 50,331,648
  const size_t wt_elems = (size_t)ORG_ * OUT_ * D_;  // 12,582,912
  const size_t need = (xb_elems + wt_elems) * sizeof(bf16);  // ~126 MB

  if (ws_size < need) {
    dim3 g(OUT_ / 64, S_ / 4, B_);
    k_gemm_fallback<<<g, dim3(64, 4), 0, stream>>>(x, oidx, w, bias, out);
    return;
  }

  bf16* xb = (bf16*)d_ws;
  bf16* wt = xb + xb_elems;

  k_cvt_x<<<2048, 256, 0, stream>>>(x, xb, (long)(xb_elems / 8));
  dim3 gt(OUT_ / 32, D_ / 32, ORG_);
  k_cvt_wT<<<gt, dim3(32, 8), 0, stream>>>(w, wt);
  k_gemm_pers<<<256, 512, 0, stream>>>(xb, wt, oidx, bias, out);
}

// Round 4
// 316.630 us; speedup vs baseline: 1.5479x; 1.5479x over previous
//
#include <hip/hip_runtime.h>
#include <hip/hip_bf16.h>
#include <stdint.h>

#define B_    8
#define S_    4096
#define D_    1536
#define ORG_  4
#define OUT_  2048

typedef __bf16 bf16;
typedef __attribute__((ext_vector_type(8)))  bf16  bf16x8;
typedef __attribute__((ext_vector_type(4)))  float f32x4;
typedef __attribute__((ext_vector_type(16))) float f32x16;

#define BK64 64
#define NKT  (D_ / BK64)   // 24 K-tiles

// ---------------- convert x: f32 -> bf16 (8 elems/thread/iter) --------------
__global__ void k_cvt_x(const float* __restrict__ x, bf16* __restrict__ xb, long n8) {
  long i = (long)blockIdx.x * blockDim.x + threadIdx.x;
  long stride = (long)gridDim.x * blockDim.x;
  for (; i < n8; i += stride) {
    const float4* p = (const float4*)(x + i * 8);
    float4 a = p[0];
    float4 b = p[1];
    bf16x8 v;
    v[0] = (bf16)a.x; v[1] = (bf16)a.y; v[2] = (bf16)a.z; v[3] = (bf16)a.w;
    v[4] = (bf16)b.x; v[5] = (bf16)b.y; v[6] = (bf16)b.z; v[7] = (bf16)b.w;
    *(bf16x8*)(xb + i * 8) = v;
  }
}

// ------ convert + transpose w: f32 [ORG][D][OUT] -> bf16 [ORG][OUT][D] ------
__global__ void k_cvt_wT(const float* __restrict__ w, bf16* __restrict__ wt) {
  __shared__ float tile[32][33];
  int org = blockIdx.z;
  int n0 = blockIdx.x * 32;   // OUT dim
  int d0 = blockIdx.y * 32;   // D dim
  const float* wsrc = w + (size_t)org * D_ * OUT_;
  bf16* wdst = wt + (size_t)org * OUT_ * D_;
  int tx = threadIdx.x, ty = threadIdx.y;
#pragma unroll
  for (int j = 0; j < 32; j += 8)
    tile[ty + j][tx] = wsrc[(size_t)(d0 + ty + j) * OUT_ + (n0 + tx)];
  __syncthreads();
#pragma unroll
  for (int j = 0; j < 32; j += 8)
    wdst[(size_t)(n0 + ty + j) * D_ + (d0 + tx)] = (bf16)tile[tx][ty + j];
}

// ----- 256x256 8-phase bf16 MFMA GEMM, 32x32x16 shape (T1+T2+T3+T4+T5) ------
// A = xb[batch] : [S][D] row-major;  B = wt[org] : [OUT][D] row-major (B^T)
// C[m][n] = sum_k A[m][k]*B[n][k]  + bias[n]
__global__ __launch_bounds__(512, 2)
void k_gemm256(const bf16* __restrict__ xb, const bf16* __restrict__ wt,
               const int* __restrict__ oidx, const float* __restrict__ bias,
               float* __restrict__ out) {
  __shared__ __align__(16) char smem[131072];   // A: 2x32KB, B: 2x32KB
  char* const ldsA = smem;
  char* const ldsB = smem + 65536;

  const int batch = blockIdx.y;
  const int bx = blockIdx.x;
  // T1: XCD-aware swizzle (128 tiles, 8 XCDs). XCD = bx&7 owns one tn column.
  const int swz = (bx & 7) * 16 + (bx >> 3);
  const int tn = swz >> 4, tm = swz & 15;
  const int m0 = tm * 256, n0 = tn * 256;
  const int org = oidx[batch];

  const bf16* Ag = xb + (size_t)batch * S_ * D_ + (size_t)m0 * D_;
  const bf16* Bg = wt + (size_t)org * OUT_ * D_ + (size_t)n0 * D_;

  const int tid  = threadIdx.x;
  const int lane = tid & 63, wv = tid >> 6;
  const int wr = wv >> 2, wc = wv & 3;        // 2x4 wave grid, per-wave 128x64 out
  const int l31 = lane & 31, hi = lane >> 5;

  // T2 read-side XOR swizzle (byte ^= (row&7)<<4 within 128B rows).
  // 32x32x16 A/B frag: lane holds row l&31, k = (lane>>5)*8 + j (ks-step k+=16).
  const int xorv = (lane & 7) << 4;
  const int off[4] = { (0  + hi * 16) ^ xorv, (32 + hi * 16) ^ xorv,
                       (64 + hi * 16) ^ xorv, (96 + hi * 16) ^ xorv };
  const int arow = (wr * 128 + l31) * 128;    // + mt*4096
  const int brow = (wc * 64  + l31) * 128;    // + nt*4096

  // Stage-side: linear LDS dest + inverse-swizzled per-lane GLOBAL source
  const int srow = tid >> 3;
  const int scol = ((tid & 7) ^ ((tid >> 3) & 7)) << 3;
  const int soff = wv * 1024;

#define LDA(v, mt, ks) (*(const bf16x8*)(ldsA + (v)*32768 + arow + (mt)*4096 + off[ks]))
#define LDB(v, nt, ks) (*(const bf16x8*)(ldsB + (v)*32768 + brow + (nt)*4096 + off[ks]))

#define STAGE_HALF(gptr, ldsbase, h, kb) do {                                            \
    __builtin_amdgcn_global_load_lds(                                                    \
      (__attribute__((address_space(1))) void*)((gptr) + (size_t)((h)*128 + srow) * D_ + (kb) + scol), \
      (__attribute__((address_space(3))) void*)((ldsbase) + (h)*16384 + soff), 16, 0, 0);\
    __builtin_amdgcn_global_load_lds(                                                    \
      (__attribute__((address_space(1))) void*)((gptr) + (size_t)((h)*128 + 64 + srow) * D_ + (kb) + scol), \
      (__attribute__((address_space(3))) void*)((ldsbase) + (h)*16384 + 8192 + soff), 16, 0, 0); \
  } while (0)

#define SBAR()  __builtin_amdgcn_s_barrier()
#define LGK0()  asm volatile("s_waitcnt lgkmcnt(0)" ::: "memory")
#define VMC4()  asm volatile("s_waitcnt vmcnt(4)" ::: "memory")
#define VMC0()  asm volatile("s_waitcnt vmcnt(0)" ::: "memory")
#define PRIO(p) __builtin_amdgcn_s_setprio(p)

  bf16x8 a[2][4], b0[4], b1[4];
  f32x16 acc[4][2];
#pragma unroll
  for (int mt = 0; mt < 4; ++mt)
#pragma unroll
    for (int nt = 0; nt < 2; ++nt)
#pragma unroll
      for (int rr = 0; rr < 16; ++rr) acc[mt][nt][rr] = 0.f;

  // 8 ds_read_b128: a-frags for one mt-pair, all 4 ks
#define READ_A2(v, mbase) do { _Pragma("unroll") for (int mm = 0; mm < 2; ++mm) \
    _Pragma("unroll") for (int ks = 0; ks < 4; ++ks) \
      a[mm][ks] = LDA(v, (mbase) + mm, ks); } while (0)
  // 4 ds_read_b128: b-frags for one nt, all 4 ks
#define READ_B4(v, nt, bb) do { _Pragma("unroll") for (int ks = 0; ks < 4; ++ks) \
      bb[ks] = LDB(v, nt, ks); } while (0)
  // 8 mfma: mt-pair x one nt x 4 ks (ks accumulates into SAME acc)
#define MFMA_O(mbase, nt, bb) do { \
    _Pragma("unroll") for (int mm = 0; mm < 2; ++mm) \
    _Pragma("unroll") for (int ks = 0; ks < 4; ++ks) \
      acc[(mbase)+mm][nt] = __builtin_amdgcn_mfma_f32_32x32x16_bf16( \
          a[mm][ks], bb[ks], acc[(mbase)+mm][nt], 0, 0, 0); } while (0)

  // ---- prologue: tile0 B+A, tile1 B (6 halves = 12 loads); newest 2 halves
  // (tile1 B) may stay outstanding at the barrier.
  STAGE_HALF(Bg, ldsB, 0, 0);
  STAGE_HALF(Bg, ldsB, 1, 0);
  STAGE_HALF(Ag, ldsA, 0, 0);
  STAGE_HALF(Ag, ldsA, 1, 0);
  STAGE_HALF(Bg, ldsB + 32768, 0, BK64);
  STAGE_HALF(Bg, ldsB + 32768, 1, BK64);
  VMC4();
  SBAR();

  for (int i = 0; i < NKT / 2; ++i) {
    const int k1 = (2 * i + 1) * BK64;
    int t2 = 2 * i + 2; if (t2 > NKT - 1) t2 = NKT - 1;   // clamp, never skip:
    int t3 = 2 * i + 3; if (t3 > NKT - 1) t3 = NKT - 1;   // keeps vmcnt math exact
    const int k2 = t2 * BK64, k3 = t3 * BK64;

    // P1: tile 2i, quad(mt0-1 x nt0); stage A-half0(2i+1) -> buf1
    READ_A2(0, 0); READ_B4(0, 0, b0);
    STAGE_HALF(Ag, ldsA + 32768, 0, k1);
    SBAR(); LGK0();
    PRIO(1); MFMA_O(0, 0, b0); PRIO(0);
    SBAR();
    // P2: quad(mt0-1 x nt1); stage A-half1(2i+1) -> buf1
    READ_B4(0, 1, b1);
    STAGE_HALF(Ag, ldsA + 32768, 1, k1);
    SBAR(); LGK0();
    PRIO(1); MFMA_O(0, 1, b1); PRIO(0);
    SBAR();
    // P3: quad(mt2-3 x nt0); stage B-half0(2i+2) -> buf0
    READ_A2(0, 2);
    STAGE_HALF(Bg, ldsB, 0, k2);
    SBAR(); LGK0();
    PRIO(1); MFMA_O(2, 0, b0); PRIO(0);
    SBAR();
    // P4: quad(mt2-3 x nt1); stage B-half1(2i+2); checkpoint vmcnt(4)
    STAGE_HALF(Bg, ldsB, 1, k2);
    SBAR();
    PRIO(1); MFMA_O(2, 1, b1); PRIO(0);
    VMC4();
    SBAR();
    // P5: tile 2i+1, quad(mt0-1 x nt0); stage A-half0(2i+2) -> buf0
    READ_A2(1, 0); READ_B4(1, 0, b0);
    STAGE_HALF(Ag, ldsA, 0, k2);
    SBAR(); LGK0();
    PRIO(1); MFMA_O(0, 0, b0); PRIO(0);
    SBAR();
    // P6: quad(mt0-1 x nt1); stage A-half1(2i+2) -> buf0
    READ_B4(1, 1, b1);
    STAGE_HALF(Ag, ldsA, 1, k2);
    SBAR(); LGK0();
    PRIO(1); MFMA_O(0, 1, b1); PRIO(0);
    SBAR();
    // P7: quad(mt2-3 x nt0); stage B-half0(2i+3) -> buf1
    READ_A2(1, 2);
    STAGE_HALF(Bg, ldsB + 32768, 0, k3);
    SBAR(); LGK0();
    PRIO(1); MFMA_O(2, 0, b0); PRIO(0);
    SBAR();
    // P8: quad(mt2-3 x nt1); stage B-half1(2i+3); checkpoint vmcnt(4)
    STAGE_HALF(Bg, ldsB + 32768, 1, k3);
    SBAR();
    PRIO(1); MFMA_O(2, 1, b1); PRIO(0);
    VMC4();
    SBAR();
  }

  VMC0();  // drain trailing (clamped) stages before stores

  // epilogue: 32x32 C/D layout col = lane&31, row = (reg&3)+8*(reg>>2)+4*(lane>>5)
  // one store instruction covers 2 full 128B lines (lanes 0-31 / 32-63).
  float* Og = out + (size_t)batch * S_ * OUT_ + (size_t)m0 * OUT_ + n0;
  const float* bbase = bias + (size_t)org * OUT_ + n0;
#pragma unroll
  for (int nt = 0; nt < 2; ++nt) {
    const int col = wc * 64 + nt * 32 + l31;
    const float bv = bbase[col];
#pragma unroll
    for (int mt = 0; mt < 4; ++mt) {
#pragma unroll
      for (int rr = 0; rr < 16; ++rr) {
        const int row = wr * 128 + mt * 32 + 4 * hi + (rr & 3) + 8 * (rr >> 2);
        Og[(size_t)row * OUT_ + col] = acc[mt][nt][rr] + bv;
      }
    }
  }
#undef LDA
#undef LDB
#undef STAGE_HALF
#undef SBAR
#undef LGK0
#undef VMC4
#undef VMC0
#undef PRIO
#undef READ_A2
#undef READ_B4
#undef MFMA_O
}

// ---------------- fallback: naive fp32 (only if ws too small) ---------------
__global__ void k_gemm_fallback(const float* __restrict__ x, const int* __restrict__ oidx,
                                const float* __restrict__ w, const float* __restrict__ bias,
                                float* __restrict__ out) {
  const int b = blockIdx.z;
  const int org = oidx[b];
  const int n = blockIdx.x * 64 + threadIdx.x;
  const int m = blockIdx.y * 4 + threadIdx.y;
  const float* xr = x + ((size_t)b * S_ + m) * D_;
  const float* wp = w + (size_t)org * D_ * OUT_ + n;
  float acc = 0.f;
  for (int k = 0; k < D_; ++k) acc += xr[k] * wp[(size_t)k * OUT_];
  out[((size_t)b * S_ + m) * OUT_ + n] = acc + bias[(size_t)org * OUT_ + n];
}

extern "C" void kernel_launch(void* const* d_in, const int* in_sizes, int n_in,
                              void* d_out, int out_size, void* d_ws, size_t ws_size,
                              hipStream_t stream) {
  const float* x    = (const float*)d_in[0];
  const int*   oidx = (const int*)d_in[1];
  const float* w    = (const float*)d_in[2];
  const float* bias = (const float*)d_in[3];
  float* out = (float*)d_out;

  const size_t xb_elems = (size_t)B_ * S_ * D_;      // 50,331,648
  const size_t wt_elems = (size_t)ORG_ * OUT_ * D_;  // 12,582,912
  const size_t need = (xb_elems + wt_elems) * sizeof(bf16);  // ~126 MB

  if (ws_size < need) {
    dim3 g(OUT_ / 64, S_ / 4, B_);
    k_gemm_fallback<<<g, dim3(64, 4), 0, stream>>>(x, oidx, w, bias, out);
    return;
  }

  bf16* xb = (bf16*)d_ws;
  bf16* wt = xb + xb_elems;

  k_cvt_x<<<2048, 256, 0, stream>>>(x, xb, (long)(xb_elems / 8));
  dim3 gt(OUT_ / 32, D_ / 32, ORG_);
  k_cvt_wT<<<gt, dim3(32, 8), 0, stream>>>(w, wt);
  dim3 gg(128, B_);
  k_gemm256<<<gg, 512, 0, stream>>>(xb, wt, oidx, bias, out);
}

// Round 5
// 305.154 us; speedup vs baseline: 1.6061x; 1.0376x over previous
//
#include <hip/hip_runtime.h>
#include <hip/hip_bf16.h>
#include <stdint.h>

#define B_    8
#define S_    4096
#define D_    1536
#define ORG_  4
#define OUT_  2048

typedef __bf16 bf16;
typedef __attribute__((ext_vector_type(8)))  bf16  bf16x8;
typedef __attribute__((ext_vector_type(4)))  float f32x4;
typedef __attribute__((ext_vector_type(16))) float f32x16;

#define BK64 64
#define NKT  (D_ / BK64)   // 24 K-tiles

// ---------------- convert x: f32 -> bf16 (8 elems/thread/iter) --------------
__global__ void k_cvt_x(const float* __restrict__ x, bf16* __restrict__ xb, long n8) {
  long i = (long)blockIdx.x * blockDim.x + threadIdx.x;
  long stride = (long)gridDim.x * blockDim.x;
  for (; i < n8; i += stride) {
    const float4* p = (const float4*)(x + i * 8);
    float4 a = p[0];
    float4 b = p[1];
    bf16x8 v;
    v[0] = (bf16)a.x; v[1] = (bf16)a.y; v[2] = (bf16)a.z; v[3] = (bf16)a.w;
    v[4] = (bf16)b.x; v[5] = (bf16)b.y; v[6] = (bf16)b.z; v[7] = (bf16)b.w;
    *(bf16x8*)(xb + i * 8) = v;
  }
}

// ------ convert + transpose w: f32 [ORG][D][OUT] -> bf16 [ORG][OUT][D] ------
__global__ void k_cvt_wT(const float* __restrict__ w, bf16* __restrict__ wt) {
  __shared__ float tile[32][33];
  int org = blockIdx.z;
  int n0 = blockIdx.x * 32;   // OUT dim
  int d0 = blockIdx.y * 32;   // D dim
  const float* wsrc = w + (size_t)org * D_ * OUT_;
  bf16* wdst = wt + (size_t)org * OUT_ * D_;
  int tx = threadIdx.x, ty = threadIdx.y;
#pragma unroll
  for (int j = 0; j < 32; j += 8)
    tile[ty + j][tx] = wsrc[(size_t)(d0 + ty + j) * OUT_ + (n0 + tx)];
  __syncthreads();
#pragma unroll
  for (int j = 0; j < 32; j += 8)
    wdst[(size_t)(n0 + ty + j) * D_ + (d0 + tx)] = (bf16)tile[tx][ty + j];
}

// ----- 256x256 8-phase bf16 MFMA GEMM, 32x32x16 shape (T1+T2+T3+T4+T5) ------
// A = xb[batch] : [S][D] row-major;  B = wt[org] : [OUT][D] row-major (B^T)
// C[m][n] = sum_k A[m][k]*B[n][k]  + bias[n]
// LDS swizzle key(r) = (r&7) ^ ((r>>3)&3): rows {r,r+8,r+16,r+24} -> distinct
// chunks, so the 32x32 fragment's row=lane&31 read is bank-conflict-free
// (max 2-way aliasing, which is free per m136).
__global__ __launch_bounds__(512, 2)
void k_gemm256(const bf16* __restrict__ xb, const bf16* __restrict__ wt,
               const int* __restrict__ oidx, const float* __restrict__ bias,
               float* __restrict__ out) {
  __shared__ __align__(16) char smem[131072];   // A: 2x32KB, B: 2x32KB
  char* const ldsA = smem;
  char* const ldsB = smem + 65536;

  const int batch = blockIdx.y;
  const int bx = blockIdx.x;
  // T1: XCD-aware swizzle (128 tiles, 8 XCDs). XCD = bx&7 owns one tn column.
  const int swz = (bx & 7) * 16 + (bx >> 3);
  const int tn = swz >> 4, tm = swz & 15;
  const int m0 = tm * 256, n0 = tn * 256;
  const int org = oidx[batch];

  const bf16* Ag = xb + (size_t)batch * S_ * D_ + (size_t)m0 * D_;
  const bf16* Bg = wt + (size_t)org * OUT_ * D_ + (size_t)n0 * D_;

  const int tid  = threadIdx.x;
  const int lane = tid & 63, wv = tid >> 6;
  const int wr = wv >> 2, wc = wv & 3;        // 2x4 wave grid, per-wave 128x64 out
  const int l31 = lane & 31, hi = lane >> 5;

  // Read-side swizzle: key(row) for row = {wr*128|wc*64}+l31 reduces to
  // (lane&7) ^ ((lane>>3)&3) for both A and B (block offsets are mult of 32).
  const int xorv = ((lane & 7) ^ ((lane >> 3) & 3)) << 4;
  const int off[4] = { (0  + hi * 16) ^ xorv, (32 + hi * 16) ^ xorv,
                       (64 + hi * 16) ^ xorv, (96 + hi * 16) ^ xorv };
  const int arow = (wr * 128 + l31) * 128;    // + mt*4096
  const int brow = (wc * 64  + l31) * 128;    // + nt*4096

  // Stage-side: linear LDS dest + inverse-swizzled per-lane GLOBAL source.
  // Physical chunk (tid&7) of row (tid>>3) holds logical chunk (tid&7)^key(row):
  const int srow = tid >> 3;
  const int scol = (((tid & 7) ^ ((tid >> 3) & 7) ^ ((tid >> 6) & 3))) << 3;
  const int soff = wv * 1024;

#define LDA(v, mt, ks) (*(const bf16x8*)(ldsA + (v)*32768 + arow + (mt)*4096 + off[ks]))
#define LDB(v, nt, ks) (*(const bf16x8*)(ldsB + (v)*32768 + brow + (nt)*4096 + off[ks]))

#define STAGE_HALF(gptr, ldsbase, h, kb) do {                                            \
    __builtin_amdgcn_global_load_lds(                                                    \
      (__attribute__((address_space(1))) void*)((gptr) + (size_t)((h)*128 + srow) * D_ + (kb) + scol), \
      (__attribute__((address_space(3))) void*)((ldsbase) + (h)*16384 + soff), 16, 0, 0);\
    __builtin_amdgcn_global_load_lds(                                                    \
      (__attribute__((address_space(1))) void*)((gptr) + (size_t)((h)*128 + 64 + srow) * D_ + (kb) + scol), \
      (__attribute__((address_space(3))) void*)((ldsbase) + (h)*16384 + 8192 + soff), 16, 0, 0); \
  } while (0)

#define SBAR()  __builtin_amdgcn_s_barrier()
#define LGK0()  asm volatile("s_waitcnt lgkmcnt(0)" ::: "memory")
#define VMC4()  asm volatile("s_waitcnt vmcnt(4)" ::: "memory")
#define VMC0()  asm volatile("s_waitcnt vmcnt(0)" ::: "memory")
#define PRIO(p) __builtin_amdgcn_s_setprio(p)

  bf16x8 a[2][4], b0[4], b1[4];
  f32x16 acc[4][2];
#pragma unroll
  for (int mt = 0; mt < 4; ++mt)
#pragma unroll
    for (int nt = 0; nt < 2; ++nt)
#pragma unroll
      for (int rr = 0; rr < 16; ++rr) acc[mt][nt][rr] = 0.f;

  // 8 ds_read_b128: a-frags for one mt-pair, all 4 ks
#define READ_A2(v, mbase) do { _Pragma("unroll") for (int mm = 0; mm < 2; ++mm) \
    _Pragma("unroll") for (int ks = 0; ks < 4; ++ks) \
      a[mm][ks] = LDA(v, (mbase) + mm, ks); } while (0)
  // 4 ds_read_b128: b-frags for one nt, all 4 ks
#define READ_B4(v, nt, bb) do { _Pragma("unroll") for (int ks = 0; ks < 4; ++ks) \
      bb[ks] = LDB(v, nt, ks); } while (0)
  // 8 mfma: mt-pair x one nt x 4 ks (ks accumulates into SAME acc)
#define MFMA_O(mbase, nt, bb) do { \
    _Pragma("unroll") for (int mm = 0; mm < 2; ++mm) \
    _Pragma("unroll") for (int ks = 0; ks < 4; ++ks) \
      acc[(mbase)+mm][nt] = __builtin_amdgcn_mfma_f32_32x32x16_bf16( \
          a[mm][ks], bb[ks], acc[(mbase)+mm][nt], 0, 0, 0); } while (0)

  // ---- prologue: tile0 B+A, tile1 B (6 halves = 12 loads); newest 2 halves
  // (tile1 B) may stay outstanding at the barrier.
  STAGE_HALF(Bg, ldsB, 0, 0);
  STAGE_HALF(Bg, ldsB, 1, 0);
  STAGE_HALF(Ag, ldsA, 0, 0);
  STAGE_HALF(Ag, ldsA, 1, 0);
  STAGE_HALF(Bg, ldsB + 32768, 0, BK64);
  STAGE_HALF(Bg, ldsB + 32768, 1, BK64);
  VMC4();
  SBAR();

  for (int i = 0; i < NKT / 2; ++i) {
    const int k1 = (2 * i + 1) * BK64;
    int t2 = 2 * i + 2; if (t2 > NKT - 1) t2 = NKT - 1;   // clamp, never skip:
    int t3 = 2 * i + 3; if (t3 > NKT - 1) t3 = NKT - 1;   // keeps vmcnt math exact
    const int k2 = t2 * BK64, k3 = t3 * BK64;

    // P1: tile 2i, quad(mt0-1 x nt0); stage A-half0(2i+1) -> buf1
    READ_A2(0, 0); READ_B4(0, 0, b0);
    STAGE_HALF(Ag, ldsA + 32768, 0, k1);
    SBAR(); LGK0();
    PRIO(1); MFMA_O(0, 0, b0); PRIO(0);
    SBAR();
    // P2: quad(mt0-1 x nt1); stage A-half1(2i+1) -> buf1
    READ_B4(0, 1, b1);
    STAGE_HALF(Ag, ldsA + 32768, 1, k1);
    SBAR(); LGK0();
    PRIO(1); MFMA_O(0, 1, b1); PRIO(0);
    SBAR();
    // P3: quad(mt2-3 x nt0); stage B-half0(2i+2) -> buf0
    READ_A2(0, 2);
    STAGE_HALF(Bg, ldsB, 0, k2);
    SBAR(); LGK0();
    PRIO(1); MFMA_O(2, 0, b0); PRIO(0);
    SBAR();
    // P4: quad(mt2-3 x nt1); stage B-half1(2i+2); checkpoint vmcnt(4)
    STAGE_HALF(Bg, ldsB, 1, k2);
    SBAR();
    PRIO(1); MFMA_O(2, 1, b1); PRIO(0);
    VMC4();
    SBAR();
    // P5: tile 2i+1, quad(mt0-1 x nt0); stage A-half0(2i+2) -> buf0
    READ_A2(1, 0); READ_B4(1, 0, b0);
    STAGE_HALF(Ag, ldsA, 0, k2);
    SBAR(); LGK0();
    PRIO(1); MFMA_O(0, 0, b0); PRIO(0);
    SBAR();
    // P6: quad(mt0-1 x nt1); stage A-half1(2i+2) -> buf0
    READ_B4(1, 1, b1);
    STAGE_HALF(Ag, ldsA, 1, k2);
    SBAR(); LGK0();
    PRIO(1); MFMA_O(0, 1, b1); PRIO(0);
    SBAR();
    // P7: quad(mt2-3 x nt0); stage B-half0(2i+3) -> buf1
    READ_A2(1, 2);
    STAGE_HALF(Bg, ldsB + 32768, 0, k3);
    SBAR(); LGK0();
    PRIO(1); MFMA_O(2, 0, b0); PRIO(0);
    SBAR();
    // P8: quad(mt2-3 x nt1); stage B-half1(2i+3); checkpoint vmcnt(4)
    STAGE_HALF(Bg, ldsB + 32768, 1, k3);
    SBAR();
    PRIO(1); MFMA_O(2, 1, b1); PRIO(0);
    VMC4();
    SBAR();
  }

  VMC0();  // drain trailing (clamped) stages before stores

  // epilogue: 32x32 C/D layout col = lane&31, row = (reg&3)+8*(reg>>2)+4*(lane>>5)
  float* Og = out + (size_t)batch * S_ * OUT_ + (size_t)m0 * OUT_ + n0;
  const float* bbase = bias + (size_t)org * OUT_ + n0;
#pragma unroll
  for (int nt = 0; nt < 2; ++nt) {
    const int col = wc * 64 + nt * 32 + l31;
    const float bv = bbase[col];
#pragma unroll
    for (int mt = 0; mt < 4; ++mt) {
#pragma unroll
      for (int rr = 0; rr < 16; ++rr) {
        const int row = wr * 128 + mt * 32 + 4 * hi + (rr & 3) + 8 * (rr >> 2);
        Og[(size_t)row * OUT_ + col] = acc[mt][nt][rr] + bv;
      }
    }
  }
#undef LDA
#undef LDB
#undef STAGE_HALF
#undef SBAR
#undef LGK0
#undef VMC4
#undef VMC0
#undef PRIO
#undef READ_A2
#undef READ_B4
#undef MFMA_O
}

// ---------------- fallback: naive fp32 (only if ws too small) ---------------
__global__ void k_gemm_fallback(const float* __restrict__ x, const int* __restrict__ oidx,
                                const float* __restrict__ w, const float* __restrict__ bias,
                                float* __restrict__ out) {
  const int b = blockIdx.z;
  const int org = oidx[b];
  const int n = blockIdx.x * 64 + threadIdx.x;
  const int m = blockIdx.y * 4 + threadIdx.y;
  const float* xr = x + ((size_t)b * S_ + m) * D_;
  const float* wp = w + (size_t)org * D_ * OUT_ + n;
  float acc = 0.f;
  for (int k = 0; k < D_; ++k) acc += xr[k] * wp[(size_t)k * OUT_];
  out[((size_t)b * S_ + m) * OUT_ + n] = acc + bias[(size_t)org * OUT_ + n];
}

extern "C" void kernel_launch(void* const* d_in, const int* in_sizes, int n_in,
                              void* d_out, int out_size, void* d_ws, size_t ws_size,
                              hipStream_t stream) {
  const float* x    = (const float*)d_in[0];
  const int*   oidx = (const int*)d_in[1];
  const float* w    = (const float*)d_in[2];
  const float* bias = (const float*)d_in[3];
  float* out = (float*)d_out;

  const size_t xb_elems = (size_t)B_ * S_ * D_;      // 50,331,648
  const size_t wt_elems = (size_t)ORG_ * OUT_ * D_;  // 12,582,912
  const size_t need = (xb_elems + wt_elems) * sizeof(bf16);  // ~126 MB

  if (ws_size < need) {
    dim3 g(OUT_ / 64, S_ / 4, B_);
    k_gemm_fallback<<<g, dim3(64, 4), 0, stream>>>(x, oidx, w, bias, out);
    return;
  }

  bf16* xb = (bf16*)d_ws;
  bf16* wt = xb + xb_elems;

  k_cvt_x<<<2048, 256, 0, stream>>>(x, xb, (long)(xb_elems / 8));
  dim3 gt(OUT_ / 32, D_ / 32, ORG_);
  k_cvt_wT<<<gt, dim3(32, 8), 0, stream>>>(w, wt);
  dim3 gg(128, B_);
  k_gemm256<<<gg, 512, 0, stream>>>(xb, wt, oidx, bias, out);
}